// Round 1
// 4180.745 us; speedup vs baseline: 1.4328x; 1.4328x over previous
//
#include <hip/hip_runtime.h>
#include <math.h>

// ---------------------------------------------------------------------------
// LSTM encoder-decoder, 3-term bf16 MFMA GEMMs (hi/lo split emulation of fp32).
//  enc: 256 steps, z = [x_t|h] @ [W;U], softmax gates
//  dec: xw precomputed once; 64 steps x 2 dirs; dense head
// All matmuls: D = Ah@Bh + Ah@Bl + Al@Bh via v_mfma_f32_16x16x32_bf16,
// fp32 accumulation. Effective ~16-bit mantissa -> fp32-class accuracy here.
// ---------------------------------------------------------------------------

typedef __attribute__((ext_vector_type(8))) short bf16x8;
typedef __attribute__((ext_vector_type(8))) unsigned short u16x8;
typedef __attribute__((ext_vector_type(4))) float f32x4;

// ws layout (float offsets)
#define OFS_CENC   0u          // 256*512 f32
#define OFS_CF     131072u     // 256*256
#define OFS_CB     196608u
#define OFS_HENCH  262144u     // 256*512 bf16 (=65536 f)
#define OFS_HENCL  327680u
#define OFS_HFH    393216u     // 256*256 bf16 (=32768 f)
#define OFS_HFL    425984u
#define OFS_HBH    458752u
#define OFS_HBL    491520u
#define OFS_ZPART  524288u     // 2 * 256*2048 f32
#define OFS_XW     1572864u    // 256*2048 f32
#define OFS_HSEQ   2097152u    // 256*64*512 bf16 (=4194304 f)
#define OFS_BENCH  6291456u    // 576*2048 bf16 packed (=589824 f)
#define OFS_BENCL  6881280u
#define OFS_BDKH   7471104u    // 512*2048 bf16 packed
#define OFS_BDKL   7995392u
#define OFS_BDUH   8519680u    // 256*2048 bf16 packed
#define OFS_BDUL   8781824u
#define WS_FLOATS  9043968u    // ~36.2 MB (< 46 MB proven available)

__device__ __forceinline__ unsigned short bf_hi(float f) {
    union { float f; unsigned u; } v; v.f = f;
    unsigned r = v.u + 0x7fffu + ((v.u >> 16) & 1u);   // round-to-nearest-even
    return (unsigned short)(r >> 16);
}
__device__ __forceinline__ float bf2f(unsigned short h) {
    union { unsigned u; float f; } v; v.u = ((unsigned)h) << 16;
    return v.f;
}
__device__ __forceinline__ void split2(float f, unsigned short& hi, unsigned short& lo) {
    hi = bf_hi(f);
    lo = bf_hi(f - bf2f(hi));
}
__device__ __forceinline__ float sigm(float x) { return 1.0f / (1.0f + __expf(-x)); }

// ---------------------------------------------------------------------------
// weight pack: fp32 [K][N-combined] -> bf16 hi/lo in frag layout [k/8][n][8]
// MODE 0: enc, K=576: k<64 -> encW[k][2048], else encU[k-64][2048]
// MODE 1: dec kernels, K=512: n<1024 -> dfK[k][1024], else dbK
// MODE 2: dec rec,     K=256: n<1024 -> dfU[k][1024], else dbU
// one thread per (kg, n) -> 8 strided reads, one 16B store per array
// ---------------------------------------------------------------------------
template <int MODE>
__global__ __launch_bounds__(256) void pack_b(
    const float* __restrict__ S0, const float* __restrict__ S1,
    unsigned short* __restrict__ H, unsigned short* __restrict__ L)
{
    const int idx = blockIdx.x * 256 + threadIdx.x;   // (K/8)*2048
    const int n = idx & 2047, kg = idx >> 11;
    u16x8 h8, l8;
    #pragma unroll
    for (int j = 0; j < 8; ++j) {
        const int k = kg * 8 + j;
        float v;
        if (MODE == 0) v = (k < 64) ? S0[(size_t)k * 2048 + n] : S1[(size_t)(k - 64) * 2048 + n];
        else           v = (n < 1024) ? S0[(size_t)k * 1024 + n] : S1[(size_t)k * 1024 + (n - 1024)];
        unsigned short hh, ll; split2(v, hh, ll);
        h8[j] = hh; l8[j] = ll;
    }
    *(u16x8*)(H + (size_t)idx * 8) = h8;
    *(u16x8*)(L + (size_t)idx * 8) = l8;
}

// ---------------------------------------------------------------------------
// 3-term MFMA GEMM. zpart[ks][256][2048] = A[256 x K/2-slice] * B
// MODE 0 (enc step): A = concat(x_t fp32 (converted inline), Henc bf16); K=576
// MODE 1 (dec proj): A = Henc bf16; K=512
// MODE 2 (dec step): A = Hf (n<1024) / Hb bf16; K=256
// Block: 256 thr = 4 waves, BM=32, BN=64. Wave (mh,nh) -> 16x32 (2 n-frags).
// No LDS, no barriers: direct global->frag loads (B pre-packed).
// ---------------------------------------------------------------------------
template <int MODE>
__global__ __launch_bounds__(256) void gemm3(
    const float* __restrict__ X,
    const unsigned short* __restrict__ AH, const unsigned short* __restrict__ AL,
    const unsigned short* __restrict__ AH2, const unsigned short* __restrict__ AL2,
    const unsigned short* __restrict__ BH, const unsigned short* __restrict__ BL,
    float* __restrict__ zpart, int t)
{
    constexpr int KW  = (MODE == 0) ? 9 : (MODE == 1 ? 8 : 4);     // k-windows per split
    constexpr int AK  = (MODE == 2) ? 256 : 512;                   // A row length (bf16 part)

    const int lane = threadIdx.x & 63, wid = threadIdx.x >> 6;
    const int mh = wid & 1, nh = wid >> 1;        // 2x2 wave grid
    const int n0 = blockIdx.x * 64;
    const int m0 = blockIdx.y * 32;
    const int ks = blockIdx.z;
    const int row  = m0 + mh * 16 + (lane & 15);  // A row (batch)
    const int l16  = lane >> 4;                   // k-group quadrant 0..3
    const int ncol = n0 + nh * 32 + (lane & 15);  // B col for frag 0

    const unsigned short* ah = AH;
    const unsigned short* al = AL;
    if (MODE == 2 && n0 >= 1024) { ah = AH2; al = AL2; }

    f32x4 acc0 = {0.f, 0.f, 0.f, 0.f}, acc1 = {0.f, 0.f, 0.f, 0.f};

    #pragma unroll
    for (int i = 0; i < KW; ++i) {
        const int kw = ks * KW + i;
        const int kg = kw * 4 + l16;              // global k-group (8 elems)
        bf16x8 a_h, a_l;
        if constexpr (MODE == 0) {
            if (kw < 2) {   // x portion (k 0..63), convert fp32 -> hi/lo inline
                const float* xp = X + (size_t)row * 16384 + t * 64 + kg * 8;
                const float4 x0 = *(const float4*)xp;
                const float4 x1 = *(const float4*)(xp + 4);
                const float xs[8] = {x0.x, x0.y, x0.z, x0.w, x1.x, x1.y, x1.z, x1.w};
                #pragma unroll
                for (int j = 0; j < 8; ++j) {
                    unsigned short hh, ll; split2(xs[j], hh, ll);
                    a_h[j] = (short)hh; a_l[j] = (short)ll;
                }
            } else {        // h portion (k 64..575)
                const size_t ao = ((size_t)row * AK) + (size_t)(kg - 8) * 8;
                a_h = *(const bf16x8*)(ah + ao);
                a_l = *(const bf16x8*)(al + ao);
            }
        } else {
            const size_t ao = ((size_t)row * AK) + (size_t)kg * 8;
            a_h = *(const bf16x8*)(ah + ao);
            a_l = *(const bf16x8*)(al + ao);
        }
        const size_t bo = ((size_t)kg * 2048 + ncol) * 8;
        const bf16x8 b_h0 = *(const bf16x8*)(BH + bo);
        const bf16x8 b_l0 = *(const bf16x8*)(BL + bo);
        const bf16x8 b_h1 = *(const bf16x8*)(BH + bo + 16 * 8);
        const bf16x8 b_l1 = *(const bf16x8*)(BL + bo + 16 * 8);

        acc0 = __builtin_amdgcn_mfma_f32_16x16x32_bf16(a_h, b_h0, acc0, 0, 0, 0);
        acc1 = __builtin_amdgcn_mfma_f32_16x16x32_bf16(a_h, b_h1, acc1, 0, 0, 0);
        acc0 = __builtin_amdgcn_mfma_f32_16x16x32_bf16(a_h, b_l0, acc0, 0, 0, 0);
        acc1 = __builtin_amdgcn_mfma_f32_16x16x32_bf16(a_h, b_l1, acc1, 0, 0, 0);
        acc0 = __builtin_amdgcn_mfma_f32_16x16x32_bf16(a_l, b_h0, acc0, 0, 0, 0);
        acc1 = __builtin_amdgcn_mfma_f32_16x16x32_bf16(a_l, b_h1, acc1, 0, 0, 0);
    }

    // C/D layout: col = lane&15, row = (lane>>4)*4 + r  [verified mapping]
    float* zp = zpart + (size_t)ks * 524288u
              + (size_t)(m0 + mh * 16 + l16 * 4) * 2048 + n0 + nh * 32 + (lane & 15);
    #pragma unroll
    for (int r = 0; r < 4; ++r) {
        zp[2048 * r]      = acc0[r];
        zp[2048 * r + 16] = acc1[r];
    }
}

// ---------------------------------------------------------------------------
// block reductions (256 threads = 4 waves)
// ---------------------------------------------------------------------------
__device__ __forceinline__ float blk_max(float v, float* red) {
    #pragma unroll
    for (int m = 32; m; m >>= 1) v = fmaxf(v, __shfl_xor(v, m, 64));
    const int wid = threadIdx.x >> 6;
    if ((threadIdx.x & 63) == 0) red[wid] = v;
    __syncthreads();
    v = fmaxf(fmaxf(red[0], red[1]), fmaxf(red[2], red[3]));
    __syncthreads();
    return v;
}
__device__ __forceinline__ float blk_sum(float v, float* red) {
    #pragma unroll
    for (int m = 32; m; m >>= 1) v += __shfl_xor(v, m, 64);
    const int wid = threadIdx.x >> 6;
    if ((threadIdx.x & 63) == 0) red[wid] = v;
    __syncthreads();
    v = red[0] + red[1] + red[2] + red[3];
    __syncthreads();
    return v;
}

// ---------------------------------------------------------------------------
// encoder gate update: one block per batch row; softmax over g and over c.
// writes h as bf16 hi/lo (consumed by next-step MFMA GEMM).
// ---------------------------------------------------------------------------
__global__ __launch_bounds__(256) void enc_update(
    const float* __restrict__ zpart, const float* __restrict__ bias,
    unsigned short* __restrict__ hH, unsigned short* __restrict__ hL,
    float* __restrict__ c)
{
    __shared__ float red[4];
    const int b = blockIdx.x, tid = threadIdx.x;
    const float* z0 = zpart + (size_t)b * 2048;
    const float* z1 = z0 + 524288u;

    float zi[2], zf[2], zg[2], zo[2];
    #pragma unroll
    for (int j = 0; j < 2; ++j) {
        const int u = tid + j * 256;
        zi[j] = bias[u]        + z0[u]        + z1[u];
        zf[j] = bias[512 + u]  + z0[u + 512]  + z1[u + 512];
        zg[j] = bias[1024 + u] + z0[u + 1024] + z1[u + 1024];
        zo[j] = bias[1536 + u] + z0[u + 1536] + z1[u + 1536];
    }
    // softmax over g (512 units)
    const float mx = blk_max(fmaxf(zg[0], zg[1]), red);
    float e[2] = {__expf(zg[0] - mx), __expf(zg[1] - mx)};
    const float inv = 1.0f / blk_sum(e[0] + e[1], red);

    float cn[2], so[2];
    #pragma unroll
    for (int j = 0; j < 2; ++j) {
        const int u = tid + j * 256;
        so[j] = sigm(zo[j]);
        const float cv = sigm(zf[j]) * c[(size_t)b * 512 + u] + sigm(zi[j]) * (e[j] * inv);
        c[(size_t)b * 512 + u] = cv;
        cn[j] = cv;
    }
    // softmax over new c (512 units)
    const float mx2 = blk_max(fmaxf(cn[0], cn[1]), red);
    float ec[2] = {__expf(cn[0] - mx2), __expf(cn[1] - mx2)};
    const float inv2 = 1.0f / blk_sum(ec[0] + ec[1], red);
    #pragma unroll
    for (int j = 0; j < 2; ++j) {
        const int u = tid + j * 256;
        const float hv = so[j] * ec[j] * inv2;
        unsigned short hh, hl; split2(hv, hh, hl);
        hH[(size_t)b * 512 + u] = hh;
        hL[(size_t)b * 512 + u] = hl;
    }
}

// ---------------------------------------------------------------------------
// dec input-projection reduce + bias fold
// ---------------------------------------------------------------------------
__global__ __launch_bounds__(256) void xw_reduce(
    const float* __restrict__ zpart, const float* __restrict__ bf,
    const float* __restrict__ bb, float* __restrict__ xw)
{
    const int i = blockIdx.x * 256 + threadIdx.x;  // 524288 total
    const int n = i & 2047;
    const float bias = (n < 1024) ? bf[n] : bb[n - 1024];
    xw[i] = zpart[i] + zpart[i + 524288] + bias;
}

// ---------------------------------------------------------------------------
// decoder gate update (tanh), both directions; writes h bf16 hi/lo + hseq bf16
// ---------------------------------------------------------------------------
__global__ __launch_bounds__(256) void dec_update(
    const float* __restrict__ zpart, const float* __restrict__ xw,
    float* __restrict__ cf, float* __restrict__ cb,
    unsigned short* __restrict__ hfH, unsigned short* __restrict__ hfL,
    unsigned short* __restrict__ hbH, unsigned short* __restrict__ hbL,
    unsigned short* __restrict__ hseqb, int step)
{
    const int idx = blockIdx.x * 256 + threadIdx.x;  // 131072 = 2*256*256
    const int u = idx & 255;
    const int b = (idx >> 8) & 255;
    const int dir = idx >> 16;
    const size_t base = (size_t)b * 2048 + dir * 1024 + u;

    const float zi = xw[base]       + zpart[base]       + zpart[524288 + base];
    const float zf = xw[base + 256] + zpart[base + 256] + zpart[524288 + base + 256];
    const float zg = xw[base + 512] + zpart[base + 512] + zpart[524288 + base + 512];
    const float zo = xw[base + 768] + zpart[base + 768] + zpart[524288 + base + 768];

    float* c = dir ? cb : cf;
    const size_t hi_ = (size_t)b * 256 + u;
    const float cv = sigm(zf) * c[hi_] + sigm(zi) * tanhf(zg);
    c[hi_] = cv;
    const float hv = sigm(zo) * tanhf(cv);

    unsigned short hh, hl; split2(hv, hh, hl);
    (dir ? hbH : hfH)[hi_] = hh;
    (dir ? hbL : hfL)[hi_] = hl;

    const int tt = dir ? (63 - step) : step;
    hseqb[((size_t)b * 64 + tt) * 512 + dir * 256 + u] = hh;  // bf16(hv) == hh
}

// ---------------------------------------------------------------------------
// final dense: out[bt][f] = hseq[bt][:] . Dk[:,f] + Db[f]  (hseq is bf16)
// ---------------------------------------------------------------------------
__global__ __launch_bounds__(256) void dense_kernel(
    const unsigned short* __restrict__ hseqb, const float* __restrict__ Dk,
    const float* __restrict__ Db, float* __restrict__ out)
{
    __shared__ float dk[8192];  // 512 x 16
    for (int i = threadIdx.x; i < 8192; i += 256) dk[i] = Dk[i];
    __syncthreads();
    const int f = threadIdx.x & 15;
    const int bt = blockIdx.x * 16 + (threadIdx.x >> 4);
    const unsigned short* hs = hseqb + (size_t)bt * 512;
    float acc = Db[f];
    #pragma unroll 4
    for (int k = 0; k < 512; k += 8) {
        const u16x8 hv = *(const u16x8*)(hs + k);
        #pragma unroll
        for (int j = 0; j < 8; ++j)
            acc += bf2f(hv[j]) * dk[(k + j) * 16 + f];
    }
    out[(size_t)bt * 16 + f] = acc;
}

__global__ __launch_bounds__(256) void zero_state(float* __restrict__ p)
{
    const int i4 = (blockIdx.x * 256 + threadIdx.x) * 4;  // 524288 floats total
    *(float4*)(p + i4) = float4{0.f, 0.f, 0.f, 0.f};
}

// ---------------------------------------------------------------------------
extern "C" void kernel_launch(void* const* d_in, const int* in_sizes, int n_in,
                              void* d_out, int out_size, void* d_ws, size_t ws_size,
                              hipStream_t stream)
{
    const float* x    = (const float*)d_in[0];   // [256][256][64]
    const float* encW = (const float*)d_in[1];   // [64][2048]
    const float* encU = (const float*)d_in[2];   // [512][2048]
    const float* encB = (const float*)d_in[3];   // [2048]
    const float* dfK  = (const float*)d_in[4];   // [512][1024]
    const float* dfU  = (const float*)d_in[5];   // [256][1024]
    const float* dfB  = (const float*)d_in[6];   // [1024]
    const float* dbK  = (const float*)d_in[7];   // [512][1024]
    const float* dbU  = (const float*)d_in[8];   // [256][1024]
    const float* dbB  = (const float*)d_in[9];   // [1024]
    const float* dK   = (const float*)d_in[10];  // [512][16]
    const float* dB   = (const float*)d_in[11];  // [16]

    if (ws_size < WS_FLOATS * sizeof(float)) return;  // ~36.2 MB scratch

    float* ws    = (float*)d_ws;
    float* cEnc  = ws + OFS_CENC;
    float* cF    = ws + OFS_CF;
    float* cB    = ws + OFS_CB;
    unsigned short* HencH = (unsigned short*)(ws + OFS_HENCH);
    unsigned short* HencL = (unsigned short*)(ws + OFS_HENCL);
    unsigned short* HfH   = (unsigned short*)(ws + OFS_HFH);
    unsigned short* HfL   = (unsigned short*)(ws + OFS_HFL);
    unsigned short* HbH   = (unsigned short*)(ws + OFS_HBH);
    unsigned short* HbL   = (unsigned short*)(ws + OFS_HBL);
    float* zpart = ws + OFS_ZPART;
    float* xw    = ws + OFS_XW;
    unsigned short* hseqb = (unsigned short*)(ws + OFS_HSEQ);
    unsigned short* BencH = (unsigned short*)(ws + OFS_BENCH);
    unsigned short* BencL = (unsigned short*)(ws + OFS_BENCL);
    unsigned short* BdkH  = (unsigned short*)(ws + OFS_BDKH);
    unsigned short* BdkL  = (unsigned short*)(ws + OFS_BDKL);
    unsigned short* BduH  = (unsigned short*)(ws + OFS_BDUH);
    unsigned short* BduL  = (unsigned short*)(ws + OFS_BDUL);

    // zero states + h packs (contiguous first 524288 floats)
    zero_state<<<512, 256, 0, stream>>>(ws);

    // pack weights into bf16 hi/lo fragment layout (once per call)
    pack_b<0><<<576, 256, 0, stream>>>(encW, encU, BencH, BencL);
    pack_b<1><<<512, 256, 0, stream>>>(dfK, dbK, BdkH, BdkL);
    pack_b<2><<<256, 256, 0, stream>>>(dfU, dbU, BduH, BduL);

    // ---- encoder: 256 sequential steps ----
    for (int t = 0; t < 256; ++t) {
        gemm3<0><<<dim3(32, 8, 2), 256, 0, stream>>>(
            x, HencH, HencL, nullptr, nullptr, BencH, BencL, zpart, t);
        enc_update<<<256, 256, 0, stream>>>(zpart, encB, HencH, HencL, cEnc);
    }

    // ---- decoder input projection (constant across time) ----
    gemm3<1><<<dim3(32, 8, 2), 256, 0, stream>>>(
        nullptr, HencH, HencL, nullptr, nullptr, BdkH, BdkL, zpart, 0);
    xw_reduce<<<2048, 256, 0, stream>>>(zpart, dfB, dbB, xw);

    // ---- decoder: 64 steps, both directions ----
    for (int s = 0; s < 64; ++s) {
        gemm3<2><<<dim3(32, 8, 2), 256, 0, stream>>>(
            nullptr, HfH, HfL, HbH, HbL, BduH, BduL, zpart, 0);
        dec_update<<<512, 256, 0, stream>>>(
            zpart, xw, cF, cB, HfH, HfL, HbH, HbL, hseqb, s);
    }

    // ---- dense head ----
    dense_kernel<<<1024, 256, 0, stream>>>(hseqb, dK, dB, (float*)d_out);
}